// Round 7
// baseline (152.331 us; speedup 1.0000x reference)
//
#include <hip/hip_runtime.h>
#include <math.h>

#define NROWS 8192
#define NF    128
#define THRF  0.004f
#define BM    64
#define BN    128
#define QN    4096
#define NITER 32          // QN / BN

typedef _Float16 f16;
typedef __attribute__((ext_vector_type(8))) _Float16 f16x8;
typedef __attribute__((ext_vector_type(4))) _Float16 f16x4;
typedef __attribute__((ext_vector_type(4))) float f32x4;
typedef __attribute__((ext_vector_type(2))) unsigned u32x2;
typedef __attribute__((address_space(3))) char lds_char;

#define MFMA16F(a, b, c) __builtin_amdgcn_mfma_f32_16x16x32_f16(a, b, c, 0, 0, 0)

// ---- LDS map: Xh j-tile (subtiled) dbuf 2x32768 + P 16384 = 81920
#define XT_OFF 0
#define PB_OFF 65536
#define SM_BYTES 81920

typedef __attribute__((address_space(1))) const unsigned int g_u32;
typedef __attribute__((address_space(3))) unsigned int l_u32;

__device__ __forceinline__ void gload16(const void* g, void* l) {
    __builtin_amdgcn_global_load_lds((g_u32*)g, (l_u32*)l, 16, 0, 0);
}

__device__ __forceinline__ unsigned short f16bits(f16 x) {
    return __builtin_bit_cast(unsigned short, x);
}

union B8 { u32x2 u2[2]; f16x8 v; };

__device__ __forceinline__ u32x2 tr8(lds_char* p) {
    u32x2 r;
    asm volatile("ds_read_b64_tr_b16 %0, %1" : "=v"(r) : "v"(p));
    return r;
}

// ---------------- prep: inv_norm^2 + fp16 hi / scaled-lo split ----------------
__global__ __launch_bounds__(256) void prep_k(const float* __restrict__ X,
                                              float* __restrict__ inv2,
                                              unsigned short* __restrict__ Xh,
                                              unsigned short* __restrict__ Xl) {
    const int t = threadIdx.x;
    const int row = blockIdx.x * 8 + (t >> 5);
    const int lane = t & 31;
    f32x4 e = reinterpret_cast<const f32x4*>(X + (size_t)row * NF)[lane];
    float ss = e[0]*e[0] + e[1]*e[1] + e[2]*e[2] + e[3]*e[3];
    ss += __shfl_xor(ss, 16); ss += __shfl_xor(ss, 8);
    ss += __shfl_xor(ss, 4);  ss += __shfl_xor(ss, 2); ss += __shfl_xor(ss, 1);
    if (lane == 0) {
        float inv = 1.0f / (sqrtf(ss) + 1e-12f);
        inv2[row] = inv * inv;
    }
    unsigned hw[2], lw[2];
    #pragma unroll
    for (int p = 0; p < 2; ++p) {
        float a = e[2*p], b = e[2*p+1];
        f16 ha = (f16)a, hb = (f16)b;
        f16 la = (f16)((a - (float)ha) * 2048.0f);
        f16 lb = (f16)((b - (float)hb) * 2048.0f);
        hw[p] = (unsigned)f16bits(ha) | ((unsigned)f16bits(hb) << 16);
        lw[p] = (unsigned)f16bits(la) | ((unsigned)f16bits(lb) << 16);
    }
    u32x2 hu = {hw[0], hw[1]}, lu = {lw[0], lw[1]};
    *reinterpret_cast<u32x2*>(Xh + (size_t)row * NF + lane * 4) = hu;
    *reinterpret_cast<u32x2*>(Xl + (size_t)row * NF + lane * 4) = lu;
}

// ---------------- staging: Xh j-tile (subtiled 4j x 16f) into buf ----------------
// LDS byte = c*1024 + lane*16. Subtile s = c*8 + (lane>>3) = jt*8 + fb with jt=c,
// fb=lane>>3; in-subtile: jr=(lane&7)>>1, half=lane&1 (row-major 4x16 f16).
__device__ __forceinline__ void stage_tile(const unsigned short* __restrict__ Xh,
                                           char* SM, int w, int l, int jwin, int buf) {
    #pragma unroll
    for (int u = 0; u < 4; ++u) {
        int c = w * 4 + u;
        int j = 4 * c + ((l & 7) >> 1);
        int f = 16 * (l >> 3) + 8 * (l & 1);
        gload16(Xh + (size_t)(jwin + j) * NF + f, SM + XT_OFF + buf * 32768 + c * 1024);
    }
}

// ---------------- fused: swapped fidelity + threshold + aggregate ----------------
__global__ __launch_bounds__(512, 2) void fused_k(const unsigned short* __restrict__ Xh,
                                                  const unsigned short* __restrict__ Xl,
                                                  const float* __restrict__ inv2,
                                                  float* __restrict__ out,
                                                  _Float16* __restrict__ p1) {
    __shared__ __align__(16) char SM[SM_BYTES];
    const int t = threadIdx.x;
    const int w = t >> 6, l = t & 63, l15 = l & 15, h = l >> 4;
    const int im = w >> 2;           // i half (GEMM1): 32 rows
    const int jn = w & 3;            // j slice (GEMM1): 32 rows
    const int ilh = w >> 2, fb = w & 3;   // GEMM2: 32-i band, 32-f band
    const int bid = blockIdx.x;
    const int ibase = (bid >> 1) * BM;
    const int qq    = bid & 1;
    const int qbase = qq * QN;

    // ---- Xi register fragments (B-operands): 2 i-subtiles x 4 ks, hi + scaled-lo
    f16x8 biH[2][4], biL[2][4];
    float invI2[2];
    #pragma unroll
    for (int it = 0; it < 2; ++it) {
        size_t ro = (size_t)(ibase + 32 * im + 16 * it + l15) * NF + 8 * h;
        #pragma unroll
        for (int ks = 0; ks < 4; ++ks) {
            biH[it][ks] = *reinterpret_cast<const f16x8*>(Xh + ro + 32 * ks);
            biL[it][ks] = *reinterpret_cast<const f16x8*>(Xl + ro + 32 * ks);
        }
        invI2[it] = inv2[ibase + 32 * im + 16 * it + l15];
    }

    f32x4 agg[2][2];
    #pragma unroll
    for (int s2 = 0; s2 < 2; ++s2)
        #pragma unroll
        for (int nf = 0; nf < 2; ++nf)
            #pragma unroll
            for (int q = 0; q < 4; ++q) agg[s2][nf][q] = 0.f;

    stage_tile(Xh, SM, w, l, qbase, 0);

    for (int it0 = 0; it0 < NITER; ++it0) {
        const int buf  = it0 & 1;
        const int jwin = qbase + it0 * BN;
        __syncthreads();                          // tiles(it0) DMA drained
        if (it0 + 1 < NITER) stage_tile(Xh, SM, w, l, jwin + BN, buf ^ 1);

        // ---- A-side operands for this wave's 32-j slice
        const char* xbuf = SM + XT_OFF + buf * 32768;
        f16x8 ahj[2][4], alg[2][4];
        f32x4 jq[2];
        #pragma unroll
        for (int jt2 = 0; jt2 < 2; ++jt2) {
            int jl = 32 * jn + 16 * jt2 + l15;
            int a_base = (jl >> 2) * 1024 + (h >> 1) * 128 + (jl & 3) * 32 + (h & 1) * 16;
            #pragma unroll
            for (int ks = 0; ks < 4; ++ks)
                ahj[jt2][ks] = *reinterpret_cast<const f16x8*>(xbuf + a_base + ks * 256);
            const unsigned short* xlr = Xl + (size_t)(jwin + jl) * NF + 8 * h;
            #pragma unroll
            for (int ks = 0; ks < 4; ++ks)
                alg[jt2][ks] = *reinterpret_cast<const f16x8*>(xlr + 32 * ks);
            jq[jt2] = *reinterpret_cast<const f32x4*>(inv2 + jwin + 32 * jn + 16 * jt2 + 4 * h);
        }

        // ---- GEMM1 (swapped): S^T[j][i] = Xj.Xi, 3-pass fp16 hi/lo
        f32x4 Shi[2][2], Slo[2][2];
        #pragma unroll
        for (int jt2 = 0; jt2 < 2; ++jt2)
            #pragma unroll
            for (int it = 0; it < 2; ++it)
                #pragma unroll
                for (int q = 0; q < 4; ++q) { Shi[jt2][it][q] = 0.f; Slo[jt2][it][q] = 0.f; }
        __builtin_amdgcn_s_setprio(1);
        #pragma unroll
        for (int ks = 0; ks < 4; ++ks) {
            #pragma unroll
            for (int jt2 = 0; jt2 < 2; ++jt2) {
                #pragma unroll
                for (int it = 0; it < 2; ++it) {
                    Shi[jt2][it] = MFMA16F(ahj[jt2][ks], biH[it][ks], Shi[jt2][it]);
                    Slo[jt2][it] = MFMA16F(alg[jt2][ks], biH[it][ks], Slo[jt2][it]);
                    Slo[jt2][it] = MFMA16F(ahj[jt2][ks], biL[it][ks], Slo[jt2][it]);
                }
            }
        }
        __builtin_amdgcn_s_setprio(0);

        // ---- threshold -> P[64 i][128 j] f16 {0,1}, swizzled, b64 writes
        #pragma unroll
        for (int jt2 = 0; jt2 < 2; ++jt2) {
            #pragma unroll
            for (int it = 0; it < 2; ++it) {
                int il = 32 * im + 16 * it + l15;
                int ecmp = (ibase + il) - (jwin + 32 * jn + 16 * jt2 + 4 * h);
                unsigned m[4];
                #pragma unroll
                for (int q = 0; q < 4; ++q) {
                    float vv = Shi[jt2][it][q] + Slo[jt2][it][q] * (1.0f / 2048.0f);
                    float t2 = vv * vv * invI2[it] * jq[jt2][q];
                    bool p = (t2 >= THRF) && (ecmp != q);
                    m[q] = p ? 0x3C00u : 0u;
                }
                int cb2 = 64 * jn + 32 * jt2 + 8 * h;
                u32x2 pw = {m[0] | (m[1] << 16), m[2] | (m[3] << 16)};
                *reinterpret_cast<u32x2*>(SM + PB_OFF + il * 256 +
                                          (cb2 ^ ((il & 7) << 4))) = pw;
            }
        }
        // light barrier: P visible; prefetch DMA stays in flight
        asm volatile("s_waitcnt lgkmcnt(0)\n\ts_barrier" ::: "memory");

        // ---- GEMM2: agg += P . Xh  (A = P swizzled b128, B = per-lane tr-reads)
        {
            lds_char* trb = (lds_char*)(SM + XT_OFF + buf * 32768);
            f16x8 bt[4][2], pa[4][2];
            #pragma unroll
            for (int kj = 0; kj < 4; ++kj) {
                #pragma unroll
                for (int nf = 0; nf < 2; ++nf) {
                    int band = 2 * fb + nf;
                    lds_char* p0 = trb + (64 * kj + 16 * h + band) * 128 + 8 * l15;
                    B8 bu;
                    bu.u2[0] = tr8(p0);
                    bu.u2[1] = tr8(p0 + 1024);
                    bt[kj][nf] = bu.v;
                }
                #pragma unroll
                for (int s2 = 0; s2 < 2; ++s2) {
                    int ir = 32 * ilh + 16 * s2 + l15;
                    pa[kj][s2] = *reinterpret_cast<const f16x8*>(
                        SM + PB_OFF + ir * 256 + ((64 * kj + 16 * h) ^ ((ir & 7) << 4)));
                }
            }
            asm volatile("s_waitcnt lgkmcnt(0)" ::: "memory");
            __builtin_amdgcn_sched_barrier(0);
            __builtin_amdgcn_s_setprio(1);
            #pragma unroll
            for (int kj = 0; kj < 4; ++kj) {
                agg[0][0] = MFMA16F(pa[kj][0], bt[kj][0], agg[0][0]);
                agg[0][1] = MFMA16F(pa[kj][0], bt[kj][1], agg[0][1]);
                agg[1][0] = MFMA16F(pa[kj][1], bt[kj][0], agg[1][0]);
                agg[1][1] = MFMA16F(pa[kj][1], bt[kj][1], agg[1][1]);
            }
            __builtin_amdgcn_s_setprio(0);
        }
    }

    // ---- store partial: row = ibase+32*ilh+16*s2+4*h+q, col = 32*fb+16*nf+l15
    #pragma unroll
    for (int s2 = 0; s2 < 2; ++s2)
        #pragma unroll
        for (int nf = 0; nf < 2; ++nf)
            #pragma unroll
            for (int q = 0; q < 4; ++q) {
                int row = ibase + 32 * ilh + 16 * s2 + 4 * h + q;
                int col = 32 * fb + 16 * nf + l15;
                float v = agg[s2][nf][q];
                if (qq == 0) out[(size_t)row * NF + col] = v;
                else         p1[(size_t)row * NF + col] = (_Float16)v;
            }
}

// ---------------- combine: sum = out + p1; out = relu(sum @ W^T) ----------------
__global__ __launch_bounds__(256) void combine_k(const _Float16* __restrict__ p1,
                                                 const float* __restrict__ Wm,
                                                 float* __restrict__ out) {
    __shared__ float sW[NF * NF];      // 64 KB
    __shared__ float sSum[32][132];
    const int t = threadIdx.x;
    const size_t base = (size_t)blockIdx.x * 32 * NF;
    #pragma unroll
    for (int k = 0; k < 16; ++k) {
        int u4 = t + 256 * k;
        reinterpret_cast<f32x4*>(sW)[u4] = reinterpret_cast<const f32x4*>(Wm)[u4];
    }
    #pragma unroll
    for (int k = 0; k < 4; ++k) {
        int u4 = t + 256 * k;                       // f32x4 / f16x4 chunk index
        f32x4 v = reinterpret_cast<const f32x4*>(out + base)[u4];
        f16x4 a = reinterpret_cast<const f16x4*>(p1 + base)[u4];
        #pragma unroll
        for (int e = 0; e < 4; ++e) v[e] += (float)a[e];
        *reinterpret_cast<f32x4*>(&sSum[u4 >> 5][(4 * u4) & 127]) = v;
    }
    __syncthreads();
    const int r = t & 31, og = t >> 5;
    float acc[16];
    #pragma unroll
    for (int oi = 0; oi < 16; ++oi) acc[oi] = 0.f;
    #pragma unroll 8
    for (int k4 = 0; k4 < 32; ++k4) {
        f32x4 a4 = *reinterpret_cast<const f32x4*>(&sSum[r][4 * k4]);
        #pragma unroll
        for (int oi = 0; oi < 16; ++oi) {
            f32x4 w4 = *reinterpret_cast<const f32x4*>(&sW[(og * 16 + oi) * NF + 4 * k4]);
            acc[oi] += a4[0] * w4[0] + a4[1] * w4[1] + a4[2] * w4[2] + a4[3] * w4[3];
        }
    }
    #pragma unroll
    for (int o4 = 0; o4 < 4; ++o4) {
        f32x4 v4;
        #pragma unroll
        for (int e = 0; e < 4; ++e) {
            float v = acc[o4 * 4 + e];
            v4[e] = v > 0.f ? v : 0.f;
        }
        *reinterpret_cast<f32x4*>(out + base + r * NF + og * 16 + o4 * 4) = v4;
    }
}

extern "C" void kernel_launch(void* const* d_in, const int* in_sizes, int n_in,
                              void* d_out, int out_size, void* d_ws, size_t ws_size,
                              hipStream_t stream) {
    const float* feat = (const float*)d_in[0];   // [8192,128] f32
    const float* Wm   = (const float*)d_in[1];   // [128,128]  f32
    float* out        = (float*)d_out;           // [8192,128] f32

    char* ws = (char*)d_ws;
    unsigned short* Xh = (unsigned short*)(ws);                      // 2 MB
    unsigned short* Xl = (unsigned short*)(ws + (2u << 20));         // 2 MB
    float* inv2        = (float*)(ws + (4u << 20));                  // 32 KB
    _Float16* p1       = (_Float16*)(ws + (4u << 20) + 32768);       // 2 MB

    prep_k<<<NROWS / 8, 256, 0, stream>>>(feat, inv2, Xh, Xl);
    fused_k<<<256, 512, 0, stream>>>(Xh, Xl, inv2, out, p1);
    combine_k<<<NROWS / 32, 256, 0, stream>>>(p1, Wm, out);
}